// Round 4
// baseline (5029.775 us; speedup 1.0000x reference)
//
#include <hip/hip_runtime.h>
#include <hip/hip_bf16.h>

// ---------------------------------------------------------------------------
// RGRL forward. N=50000 nodes, E=800000 edges, D=H=PH=512, R=TOPK=256, K=8.
// f32 math (reference is f32; no fp32 MFMA on CDNA4 -> vector-ALU GEMM).
// Structure:
//  - layer-1 aggregation hoisted BEFORE the linear map (agg(x@W)==agg(x)@W),
//    shared between student & teacher encoders: 4 F=512 agg passes -> 2.
//  - 128x128-tile / 8x8-microtile f32 GEMM (2 FLOP per LDS byte).
//  - scratch parked inside dead d_out slots: ws need ~219 MB.
// ---------------------------------------------------------------------------

#define N_NODES 50000
#define N_EDGES 800000

// ---------------- tiny zero kernel (graph-capture-safe memset) ---------------
__global__ void k_zero(int* __restrict__ p, int n) {
    int i = blockIdx.x * blockDim.x + threadIdx.x;
    if (i < n) p[i] = 0;
}

// ---------------- CSR build --------------------------------------------------
__global__ void k_deg(const int* __restrict__ ei, int E, int* __restrict__ cnt) {
    int e = blockIdx.x * blockDim.x + threadIdx.x;
    if (e < E) atomicAdd(&cnt[ei[E + e]], 1);   // ei[1][e] = dst
}

// 2-block kernel: block 0 scans graph1 degrees, block 1 graph2 (shuffle scan).
__global__ void k_scan2(const int* __restrict__ d1, int* __restrict__ o1,
                        const int* __restrict__ d2, int* __restrict__ o2, int n) {
    const int* deg = blockIdx.x ? d2 : d1;
    int* offs      = blockIdx.x ? o2 : o1;
    __shared__ int wsum[16];
    __shared__ int carry_s;
    int t = threadIdx.x;
    int lane = t & 63, wid = t >> 6;
    if (t == 0) { carry_s = 0; offs[0] = 0; }
    __syncthreads();
    for (int base = 0; base < n; base += 1024) {
        int v = (base + t < n) ? deg[base + t] : 0;
        int s = v;
#pragma unroll
        for (int off = 1; off < 64; off <<= 1) {
            int x = __shfl_up(s, off);
            if (lane >= off) s += x;
        }
        if (lane == 63) wsum[wid] = s;
        __syncthreads();
        if (wid == 0) {
            int ws = (lane < 16) ? wsum[lane] : 0;
#pragma unroll
            for (int off = 1; off < 16; off <<= 1) {
                int x = __shfl_up(ws, off);
                if (lane >= off) ws += x;
            }
            if (lane < 16) wsum[lane] = ws;
        }
        __syncthreads();
        int prefix = carry_s + (wid ? wsum[wid - 1] : 0);
        if (base + t < n) offs[base + t + 1] = prefix + s;
        int total = wsum[15];
        __syncthreads();
        if (t == 0) carry_s += total;
        __syncthreads();
    }
}

__global__ void k_copy(const int* __restrict__ src, int* __restrict__ dst, int n) {
    int i = blockIdx.x * blockDim.x + threadIdx.x;
    if (i < n) dst[i] = src[i];
}

__global__ void k_place(const int* __restrict__ ei, const float* __restrict__ ew, int E,
                        int* __restrict__ cursor, int* __restrict__ csr_src,
                        float* __restrict__ csr_w) {
    int e = blockIdx.x * blockDim.x + threadIdx.x;
    if (e < E) {
        int dst = ei[E + e];
        int pos = atomicAdd(&cursor[dst], 1);
        csr_src[pos] = ei[e];
        csr_w[pos]   = ew[e];
    }
}

// ---------------- weighted neighbor-sum (+ optional PReLU) -------------------
// one WAVE per node: blockDim=256 (4 waves -> 4 nodes/block).
// F=512: 2 float4/lane; F=256: 1 float4/lane. Gathers are 1KB-coalesced.
template <int F, bool PRELU>
__global__ __launch_bounds__(256) void k_agg(
        const float* __restrict__ H, const int* __restrict__ offs,
        const int* __restrict__ src, const float* __restrict__ wgt,
        const float* __restrict__ a_ptr, float* __restrict__ out, int nnodes) {
    constexpr int NV = F / 256;               // float4 per lane
    int wid  = threadIdx.x >> 6;
    int lane = threadIdx.x & 63;
    int node = blockIdx.x * 4 + wid;
    if (node >= nnodes) return;
    float4 acc[NV];
#pragma unroll
    for (int v = 0; v < NV; ++v) acc[v] = make_float4(0.f, 0.f, 0.f, 0.f);
    int s = offs[node], e = offs[node + 1];
    for (int i = s; i < e; ++i) {
        int sn = src[i];
        float w = wgt[i];
        const float* hp = H + (size_t)sn * F + lane * 4;
#pragma unroll
        for (int v = 0; v < NV; ++v) {
            float4 h = *(const float4*)(hp + v * 256);
            acc[v].x += w * h.x; acc[v].y += w * h.y;
            acc[v].z += w * h.z; acc[v].w += w * h.w;
        }
    }
    if (PRELU) {
        float a = *a_ptr;
#pragma unroll
        for (int v = 0; v < NV; ++v) {
            acc[v].x = acc[v].x >= 0.f ? acc[v].x : a * acc[v].x;
            acc[v].y = acc[v].y >= 0.f ? acc[v].y : a * acc[v].y;
            acc[v].z = acc[v].z >= 0.f ? acc[v].z : a * acc[v].z;
            acc[v].w = acc[v].w >= 0.f ? acc[v].w : a * acc[v].w;
        }
    }
    float* op = out + (size_t)node * F + lane * 4;
#pragma unroll
    for (int v = 0; v < NV; ++v) *(float4*)(op + v * 256) = acc[v];
}

// ---------------- f32 tiled GEMM ---------------------------------------------
// C[N x O] = alpha*(A[N x K] @ W[K x O]) + bias, optional PReLU.
// 128x128 tile, 256 threads, 8x8 microtile as 2x(4-row) x 2x(4-col) stride-64
// groups -> LDS fragment reads are broadcast / 2-way (free). 2 FLOP/LDS-byte.
__global__ __launch_bounds__(256) void gemm_f32(
    const float* __restrict__ A, const float* __restrict__ W, float* __restrict__ C,
    int N, int K, int O, const float* __restrict__ bias,
    const float* __restrict__ prelu_a, float alpha)
{
    __shared__ float As[16][132];
    __shared__ float Ws[16][132];

    int tid = threadIdx.x;
    int tx = tid & 15;           // col group
    int ty = tid >> 4;           // row group
    int row0 = blockIdx.y * 128;
    int col0 = blockIdx.x * 128;

    float acc[8][8] = {};

    int am  = tid >> 2;          // 0..63 : A tile row (and +64)
    int akq = tid & 3;           // float4 index within 16-wide K slice
    int wkk = tid >> 4;          // 0..15 : K row for W load
    int wnq = tid & 15;          // float4 col group (and +64)

    bool ok0 = (row0 + am)      < N;
    bool ok1 = (row0 + am + 64) < N;
    const float* Ap0 = A + (size_t)(row0 + am)      * K + akq * 4;
    const float* Ap1 = A + (size_t)(row0 + am + 64) * K + akq * 4;
    const float* Wp  = W + (size_t)wkk * O + col0 + wnq * 4;

    const float4 z4 = make_float4(0.f, 0.f, 0.f, 0.f);

    for (int k0 = 0; k0 < K; k0 += 16) {
        float4 a0 = ok0 ? *(const float4*)(Ap0 + k0) : z4;
        float4 a1 = ok1 ? *(const float4*)(Ap1 + k0) : z4;
        float4 w0 = *(const float4*)(Wp + (size_t)k0 * O);
        float4 w1 = *(const float4*)(Wp + (size_t)k0 * O + 64);

        As[akq * 4 + 0][am] = a0.x;
        As[akq * 4 + 1][am] = a0.y;
        As[akq * 4 + 2][am] = a0.z;
        As[akq * 4 + 3][am] = a0.w;
        As[akq * 4 + 0][am + 64] = a1.x;
        As[akq * 4 + 1][am + 64] = a1.y;
        As[akq * 4 + 2][am + 64] = a1.z;
        As[akq * 4 + 3][am + 64] = a1.w;
        *(float4*)&Ws[wkk][wnq * 4]      = w0;
        *(float4*)&Ws[wkk][wnq * 4 + 64] = w1;
        __syncthreads();

#pragma unroll
        for (int kk = 0; kk < 16; ++kk) {
            float4 aL = *(const float4*)&As[kk][ty * 4];
            float4 aH = *(const float4*)&As[kk][64 + ty * 4];
            float4 bL = *(const float4*)&Ws[kk][tx * 4];
            float4 bH = *(const float4*)&Ws[kk][64 + tx * 4];
            float av_[8] = {aL.x, aL.y, aL.z, aL.w, aH.x, aH.y, aH.z, aH.w};
            float bv_[8] = {bL.x, bL.y, bL.z, bL.w, bH.x, bH.y, bH.z, bH.w};
#pragma unroll
            for (int i = 0; i < 8; ++i)
#pragma unroll
                for (int j = 0; j < 8; ++j)
                    acc[i][j] += av_[i] * bv_[j];
        }
        __syncthreads();
    }

    float pa = prelu_a ? *prelu_a : 0.f;
    float bL[4] = {0.f, 0.f, 0.f, 0.f}, bH[4] = {0.f, 0.f, 0.f, 0.f};
    if (bias) {
#pragma unroll
        for (int j = 0; j < 4; ++j) {
            bL[j] = bias[col0 + tx * 4 + j];
            bH[j] = bias[col0 + 64 + tx * 4 + j];
        }
    }
#pragma unroll
    for (int i = 0; i < 8; ++i) {
        int r = row0 + (i < 4 ? ty * 4 + i : 64 + ty * 4 + (i - 4));
        if (r < N) {
            float4 oL, oH;
            oL.x = acc[i][0] * alpha + bL[0];
            oL.y = acc[i][1] * alpha + bL[1];
            oL.z = acc[i][2] * alpha + bL[2];
            oL.w = acc[i][3] * alpha + bL[3];
            oH.x = acc[i][4] * alpha + bH[0];
            oH.y = acc[i][5] * alpha + bH[1];
            oH.z = acc[i][6] * alpha + bH[2];
            oH.w = acc[i][7] * alpha + bH[3];
            if (prelu_a) {
                oL.x = oL.x >= 0.f ? oL.x : pa * oL.x;
                oL.y = oL.y >= 0.f ? oL.y : pa * oL.y;
                oL.z = oL.z >= 0.f ? oL.z : pa * oL.z;
                oL.w = oL.w >= 0.f ? oL.w : pa * oL.w;
                oH.x = oH.x >= 0.f ? oH.x : pa * oH.x;
                oH.y = oH.y >= 0.f ? oH.y : pa * oH.y;
                oH.z = oH.z >= 0.f ? oH.z : pa * oH.z;
                oH.w = oH.w >= 0.f ? oH.w : pa * oH.w;
            }
            *(float4*)(C + (size_t)r * O + col0 + tx * 4)      = oL;
            *(float4*)(C + (size_t)r * O + col0 + 64 + tx * 4) = oH;
        }
    }
}

// ---------------- row-wise l2 normalization (rows of 256), in place ----------
__global__ void k_l2norm(float* __restrict__ X, int n) {
    int idx = blockIdx.x * blockDim.x + threadIdx.x;
    int row = idx >> 6, lane = idx & 63;
    if (row >= n) return;
    float4* p = (float4*)(X + (size_t)row * 256 + lane * 4);
    float4 v = *p;
    float ss = v.x * v.x + v.y * v.y + v.z * v.z + v.w * v.w;
#pragma unroll
    for (int off = 32; off; off >>= 1) ss += __shfl_xor(ss, off);
    float inv = 1.0f / fmaxf(sqrtf(ss), 1e-12f);
    v.x *= inv; v.y *= inv; v.z *= inv; v.w *= inv;
    *p = v;
}

// ---------------- gather sampled teacher rows, transposed: outT[r*256+i] -----
__global__ void k_gatherT(const float* __restrict__ T, const int* __restrict__ sample,
                          float* __restrict__ outT) {
    int i = blockIdx.x;      // sample index 0..255
    int r = threadIdx.x;     // feature 0..255
    int s = sample[i];
    outT[r * 256 + i] = T[(size_t)s * 256 + r];
}

// ---------------- diffusion-neighbor dot products ----------------------------
// out_q[i,k] = 2*dot(Tn[diff[nz[i],k]], Pn[nz[i]]); out_k same with Tn[nz[i]]
__global__ void k_diff(const float* __restrict__ Tn, const float* __restrict__ Pn,
                       const int* __restrict__ diff, const int* __restrict__ nz,
                       float* __restrict__ out_q, float* __restrict__ out_k, int n) {
    int idx = blockIdx.x * blockDim.x + threadIdx.x;
    int row = idx >> 6, lane = idx & 63;
    if (row >= n) return;
    int node = nz[row];
    float4 p  = *(const float4*)(Pn + (size_t)node * 256 + lane * 4);
    float4 tn = *(const float4*)(Tn + (size_t)node * 256 + lane * 4);
#pragma unroll
    for (int k = 0; k < 8; ++k) {
        int m = diff[node * 8 + k];
        float4 d = *(const float4*)(Tn + (size_t)m * 256 + lane * 4);
        float sq = d.x * p.x + d.y * p.y + d.z * p.z + d.w * p.w;
        float sk = d.x * tn.x + d.y * tn.y + d.z * tn.z + d.w * tn.w;
#pragma unroll
        for (int off = 32; off; off >>= 1) {
            sq += __shfl_xor(sq, off);
            sk += __shfl_xor(sk, off);
        }
        if (lane == 0) {
            out_q[(size_t)row * 8 + k] = 2.f * sq;
            out_k[(size_t)row * 8 + k] = 2.f * sk;
        }
    }
}

// ---------------------------------------------------------------------------
extern "C" void kernel_launch(void* const* d_in, const int* in_sizes, int n_in,
                              void* d_out, int out_size, void* d_ws, size_t ws_size,
                              hipStream_t stream) {
    const float* x1   = (const float*)d_in[0];
    const float* x2   = (const float*)d_in[1];
    const int*   ei1  = (const int*)d_in[2];
    const int*   ei2  = (const int*)d_in[3];
    const float* ew1  = (const float*)d_in[4];
    const float* ew2  = (const float*)d_in[5];
    const int*   diff = (const int*)d_in[6];
    const int*   samp = (const int*)d_in[7];
    const int*   notz = (const int*)d_in[8];
    const float* Ws1  = (const float*)d_in[9];
    const float* as1  = (const float*)d_in[10];
    const float* Ws2  = (const float*)d_in[11];
    const float* as2  = (const float*)d_in[12];
    const float* Wp1  = (const float*)d_in[13];
    const float* bp1  = (const float*)d_in[14];
    const float* ap   = (const float*)d_in[15];
    const float* Wp2  = (const float*)d_in[16];
    const float* bp2  = (const float*)d_in[17];
    const float* Wt1  = (const float*)d_in[18];
    const float* at1  = (const float*)d_in[19];
    const float* Wt2  = (const float*)d_in[20];
    const float* at2  = (const float*)d_in[21];

    const int N = N_NODES, E = N_EDGES;
    float* out = (float*)d_out;

    // d_out flat offsets (floats), reference return order
    const size_t off_q1  = 0;           // 12.8M
    const size_t off_q1d = 12800000;    // 0.4M
    const size_t off_k1  = 13200000;    // 12.8M
    const size_t off_k1d = 26000000;    // 0.4M
    const size_t off_q2  = 26400000;    // 12.8M
    const size_t off_q2d = 39200000;    // 0.4M
    const size_t off_k2  = 39600000;    // 12.8M
    const size_t off_k2d = 52400000;    // 0.4M
    const size_t off_s1  = 52800000;    // 12.8M

    // ---- workspace bump allocator (~219 MB) ----
    char* wp = (char*)d_ws;
    auto alloc = [&](size_t bytes) -> void* {
        void* r = (void*)wp;
        wp += (bytes + 255) & ~(size_t)255;
        return r;
    };
    float* aggX  = (float*)alloc((size_t)N * 512 * 4);   // agg(x) shared; later pred1|pred2
    float* bufH  = (float*)alloc((size_t)N * 512 * 4);   // layer-1 h / predictor hidden
    float* t1sT  = (float*)alloc((size_t)256 * 256 * 4);
    float* t2sT  = (float*)alloc((size_t)256 * 256 * 4);
    int*   offs1 = (int*)alloc((size_t)(N + 1) * 4);
    int*   cur1  = (int*)alloc((size_t)N * 4);
    int*   src1  = (int*)alloc((size_t)E * 4);
    float* w1    = (float*)alloc((size_t)E * 4);
    int*   offs2 = (int*)alloc((size_t)(N + 1) * 4);
    int*   cur2  = (int*)alloc((size_t)N * 4);
    int*   src2  = (int*)alloc((size_t)E * 4);
    float* w2    = (float*)alloc((size_t)E * 4);

    // scratch parked in dead d_out slots (freed by final sim-GEMM order):
    float* bufT   = out + off_k1;   // layer-2 pre-agg (N x 256); dead before k1 GEMM
    float* s2     = out + off_k2;   // student2; dead before k2 GEMM
    float* teach1 = out + off_q1;   // parked; killed by q1 GEMM (after k2 GEMM reads it)
    float* teach2 = out + off_q2;   // parked; killed by q2 GEMM (after k1 GEMM reads it)
    float* stud1  = out + off_s1;   // student1 is itself an output
    float* pred1  = aggX;           // aggX dead after encoders
    float* pred2  = aggX + (size_t)N * 256;

    // ---- CSR build (both graphs) ----
    k_zero<<<(N + 255) / 256, 256, 0, stream>>>(cur1, N);
    k_zero<<<(N + 255) / 256, 256, 0, stream>>>(cur2, N);
    int eblocks = (E + 255) / 256;
    k_deg<<<eblocks, 256, 0, stream>>>(ei1, E, cur1);
    k_deg<<<eblocks, 256, 0, stream>>>(ei2, E, cur2);
    k_scan2<<<2, 1024, 0, stream>>>(cur1, offs1, cur2, offs2, N);
    k_copy<<<(N + 255) / 256, 256, 0, stream>>>(offs1, cur1, N);
    k_copy<<<(N + 255) / 256, 256, 0, stream>>>(offs2, cur2, N);
    k_place<<<eblocks, 256, 0, stream>>>(ei1, ew1, E, cur1, src1, w1);
    k_place<<<eblocks, 256, 0, stream>>>(ei2, ew2, E, cur2, src2, w2);

    auto gemm = [&](const float* A_, const float* W_, float* C_, int n, int k, int o,
                    const float* bias, const float* pa, float alpha) {
        dim3 g(o / 128, (n + 127) / 128);
        gemm_f32<<<g, 256, 0, stream>>>(A_, W_, C_, n, k, o, bias, pa, alpha);
    };
    int ablocks = (N + 3) / 4;

    // encoder tail: h(=PReLU(aggX@W1)) -> W2 -> agg(+PReLU) -> dest
    auto enc_tail = [&](const float* W1, const float* a1, const float* W2,
                        const float* a2, const int* offs, const int* src,
                        const float* w, float* dest) {
        gemm(aggX, W1, bufH, N, 512, 512, nullptr, a1, 1.f);     // PReLU fused
        gemm(bufH, W2, bufT, N, 512, 256, nullptr, nullptr, 1.f);
        k_agg<256, true><<<ablocks, 256, 0, stream>>>(bufT, offs, src, w, a2, dest, N);
    };

    // ---- graph 1: shared layer-1 aggregate, then student1 + teacher1 ----
    k_agg<512, false><<<ablocks, 256, 0, stream>>>(x1, offs1, src1, w1, nullptr, aggX, N);
    enc_tail(Ws1, as1, Ws2, as2, offs1, src1, w1, stud1);
    enc_tail(Wt1, at1, Wt2, at2, offs1, src1, w1, teach1);

    // ---- graph 2 ----
    k_agg<512, false><<<ablocks, 256, 0, stream>>>(x2, offs2, src2, w2, nullptr, aggX, N);
    enc_tail(Ws1, as1, Ws2, as2, offs2, src2, w2, s2);
    enc_tail(Wt1, at1, Wt2, at2, offs2, src2, w2, teach2);
    // aggX now dead -> reused as pred1|pred2

    // ---- teacher l2norm (in place) ----
    int nwblocks = ((N * 64) + 255) / 256;
    k_l2norm<<<nwblocks, 256, 0, stream>>>(teach1, N);
    k_l2norm<<<nwblocks, 256, 0, stream>>>(teach2, N);

    // ---- predictors + l2norm ----
    gemm(stud1, Wp1, bufH, N, 256, 512, bp1, ap, 1.f);           // hid1 (bias+PReLU)
    gemm(bufH, Wp2, pred1, N, 512, 256, bp2, nullptr, 1.f);
    k_l2norm<<<nwblocks, 256, 0, stream>>>(pred1, N);
    gemm(s2, Wp1, bufH, N, 256, 512, bp1, ap, 1.f);              // hid2
    gemm(bufH, Wp2, pred2, N, 512, 256, bp2, nullptr, 1.f);
    k_l2norm<<<nwblocks, 256, 0, stream>>>(pred2, N);

    // ---- sampled-teacher gathers (transposed for NN gemm) ----
    k_gatherT<<<256, 256, 0, stream>>>(teach2, samp, t2sT);
    k_gatherT<<<256, 256, 0, stream>>>(teach1, samp, t1sT);

    // ---- diffusion sims (need teach1/teach2 intact) ----
    k_diff<<<nwblocks, 256, 0, stream>>>(teach2, pred1, diff, notz,
                                         out + off_q1d, out + off_k1d, N);
    k_diff<<<nwblocks, 256, 0, stream>>>(teach1, pred2, diff, notz,
                                         out + off_q2d, out + off_k2d, N);

    // ---- sim GEMMs. Order matters for the out-slot parking:
    //  k1 (kills bufT, reads teach2) -> k2 (kills s2, reads teach1)
    //  -> q1 (kills teach1, reads pred1) -> q2 (kills teach2, reads pred2)
    gemm(teach2, t2sT, out + off_k1, N, 256, 256, nullptr, nullptr, 2.f);
    gemm(teach1, t1sT, out + off_k2, N, 256, 256, nullptr, nullptr, 2.f);
    gemm(pred1,  t2sT, out + off_q1, N, 256, 256, nullptr, nullptr, 2.f);
    gemm(pred2,  t1sT, out + off_q2, N, 256, 256, nullptr, nullptr, 2.f);
}